// Round 8
// baseline (388.291 us; speedup 1.0000x reference)
//
#include <hip/hip_runtime.h>
#include <stdint.h>

typedef unsigned short u16;
typedef unsigned int u32;
typedef __bf16 bf16x8 __attribute__((ext_vector_type(8)));
typedef float f32x4 __attribute__((ext_vector_type(4)));
typedef float f32x16 __attribute__((ext_vector_type(16)));

#define MFMA16 __builtin_amdgcn_mfma_f32_16x16x32_bf16
#define MFMA32 __builtin_amdgcn_mfma_f32_32x32x16_bf16

static __device__ __forceinline__ u16 f2bf(float f) {
  union { float f; u32 u; } v; v.f = f;
  u32 r = v.u + 0x7FFFu + ((v.u >> 16) & 1u);
  return (u16)(r >> 16);
}
static __device__ __forceinline__ float bf2f(u16 b) {
  union { float f; u32 u; } v; v.u = ((u32)b) << 16;
  return v.f;
}
static __device__ __forceinline__ void load_lds16(const void* g, void* l) {
  __builtin_amdgcn_global_load_lds(
      (const __attribute__((address_space(1))) void*)g,
      (__attribute__((address_space(3))) void*)l, 16, 0, 0);
}
static __device__ __forceinline__ void keep(u32 x) {
  asm volatile("" :: "v"(x));  // rule #17: keep value live, ~0 cost
}

// ---------------- fp32 -> bf16 convert (vectorized) ----------------
__global__ __launch_bounds__(256) void cvt_bf16(const float* __restrict__ in,
                                                u16* __restrict__ out, int n4) {
  int i = blockIdx.x * 256 + threadIdx.x;
  if (i >= n4) return;
  float4 v = reinterpret_cast<const float4*>(in)[i];
  uint2 r;
  r.x = (u32)f2bf(v.x) | ((u32)f2bf(v.y) << 16);
  r.y = (u32)f2bf(v.z) | ((u32)f2bf(v.w) << 16);
  reinterpret_cast<uint2*>(out)[i] = r;
}

// ---------------- bf16 GEMM, C[M][N] = A[M][K] @ B[N][K]^T ----------------
template <bool OUT_BF16>
__global__ __launch_bounds__(256, 2) void gemm_bt(const u16* __restrict__ A,
                                                  const u16* __restrict__ B,
                                                  void* __restrict__ Cv,
                                                  int M, int N, int K) {
  __shared__ u16 As[128 * 32];
  __shared__ u16 Bs[128 * 32];
  const int t = threadIdx.x;
  const int w = t >> 6, lane = t & 63;
  const int brow = blockIdx.y * 128, bcol = blockIdx.x * 128;
  const int wr = (w >> 1) * 64, wc = (w & 1) * 64;

  f32x4 acc[4][4];
#pragma unroll
  for (int i = 0; i < 4; ++i)
#pragma unroll
    for (int j = 0; j < 4; ++j) acc[i][j] = (f32x4){0.f, 0.f, 0.f, 0.f};

  const int srow = w * 16 + (lane >> 2);
  const int scol = (lane & 3) * 8;
  const u16* ga = A + (size_t)(brow + srow) * K + scol;
  const u16* gb = B + (size_t)(bcol + srow) * K + scol;
  const size_t rstep = (size_t)64 * K;
  u16* ldsA = As + w * 512;
  u16* ldsB = Bs + w * 512;

  const int lc = lane & 15, lg = lane >> 4;
  const int kg = lg * 8;

  const int nk = K >> 5;
  for (int kt = 0; kt < nk; ++kt) {
    __syncthreads();
    load_lds16(ga, ldsA);
    load_lds16(ga + rstep, (char*)ldsA + 4096);
    load_lds16(gb, ldsB);
    load_lds16(gb + rstep, (char*)ldsB + 4096);
    ga += 32; gb += 32;
    asm volatile("s_waitcnt vmcnt(0)" ::: "memory");
    __syncthreads();
    bf16x8 af[4], bfr[4];
#pragma unroll
    for (int i = 0; i < 4; ++i)
      af[i] = *reinterpret_cast<const bf16x8*>(As + (wr + i * 16 + lc) * 32 + kg);
#pragma unroll
    for (int j = 0; j < 4; ++j)
      bfr[j] = *reinterpret_cast<const bf16x8*>(Bs + (wc + j * 16 + lc) * 32 + kg);
#pragma unroll
    for (int i = 0; i < 4; ++i)
#pragma unroll
      for (int j = 0; j < 4; ++j)
        acc[i][j] = MFMA16(af[i], bfr[j], acc[i][j], 0, 0, 0);
  }

  const int r0 = lg * 4;
#pragma unroll
  for (int i = 0; i < 4; ++i)
#pragma unroll
    for (int j = 0; j < 4; ++j)
#pragma unroll
      for (int r = 0; r < 4; ++r) {
        const int m = brow + wr + i * 16 + r0 + r;
        const int n = bcol + wc + j * 16 + lc;
        if constexpr (OUT_BF16)
          ((u16*)Cv)[(size_t)m * N + n] = f2bf(acc[i][j][r]);
        else
          ((float*)Cv)[(size_t)m * N + n] = acc[i][j][r];
      }
}

// ---------------- RoPE trig table: [s][pair] -> (cos, sin) ----------------
__global__ __launch_bounds__(256) void build_trig(const int* __restrict__ pos,
                                                  float2* __restrict__ tab) {
  int i = blockIdx.x * 256 + threadIdx.x;
  int s = i >> 5, p = i & 31;
  float inv = powf(10000.0f, -(float)p * (1.0f / 32.0f));
  float fr = (float)pos[s] * inv;
  float sn, cs;
  sincosf(fr, &sn, &cs);
  tab[i] = make_float2(cs, sn);
}

// ------- RoPE + repack q,k -> [B*H][S][64]  (q pre-scaled 0.125*log2e) -----
__global__ __launch_bounds__(256) void rope_repack(const u16* __restrict__ qkv,
                                                   const float2* __restrict__ tab,
                                                   u16* __restrict__ Qro,
                                                   u16* __restrict__ Kro) {
  int idx = blockIdx.x * 256 + threadIdx.x;
  int p = idx & 31;
  int h = (idx >> 5) & 15;
  int m = idx >> 9;
  int b = m >> 11, s = m & 2047;
  const u32* row = reinterpret_cast<const u32*>(qkv + (size_t)m * 3072);
  u32 qp = row[h * 32 + p];
  u32 kp = row[512 + h * 32 + p];
  float2 cssn = tab[s * 32 + p];
  float cs = cssn.x, sn = cssn.y;
  float qe = bf2f((u16)(qp & 0xffffu)), qo = bf2f((u16)(qp >> 16));
  float ke = bf2f((u16)(kp & 0xffffu)), ko = bf2f((u16)(kp >> 16));
  const float QS = 0.18033688011112042f;  // 0.125 * log2(e)
  float qre = (qe * cs - qo * sn) * QS;
  float qro_ = (qe * sn + qo * cs) * QS;
  float kre = ke * cs - ko * sn;
  float kro_ = ke * sn + ko * cs;
  size_t o = ((size_t)(b * 16 + h) * 2048 + s) * 32 + p;
  reinterpret_cast<u32*>(Qro)[o] = (u32)f2bf(qre) | ((u32)f2bf(qro_) << 16);
  reinterpret_cast<u32*>(Kro)[o] = (u32)f2bf(kre) | ((u32)f2bf(kro_) << 16);
}

// ---------------- V -> V^T   ([B*H][S][64] slice of qkv -> [B*H][64][S]) ----
__global__ __launch_bounds__(256) void v_transpose(const u16* __restrict__ qkv,
                                                   u16* __restrict__ VT) {
  const int bh = blockIdx.y;
  const int s0 = blockIdx.x * 64;
  const int b = bh >> 4, h = bh & 15;
  __shared__ u16 tile[64][72];
  const int t = threadIdx.x;
#pragma unroll
  for (int c = 0; c < 2; ++c) {
    int r = c * 32 + (t >> 3);
    int d = (t & 7) * 8;
    const u16* src = qkv + (size_t)(b * 2048 + s0 + r) * 3072 + 2048 + h * 64 + d;
    *reinterpret_cast<uint4*>(&tile[r][d]) = *reinterpret_cast<const uint4*>(src);
  }
  __syncthreads();
#pragma unroll
  for (int c = 0; c < 2; ++c) {
    int dd = c * 32 + (t >> 3);
    int sg = (t & 7) * 8;
    u16 tmp[8];
#pragma unroll
    for (int jj = 0; jj < 8; ++jj) tmp[jj] = tile[sg + jj][dd];
    *reinterpret_cast<uint4*>(VT + ((size_t)bh * 64 + dd) * 2048 + s0 + sg) =
        *reinterpret_cast<const uint4*>(tmp);
  }
}

// ======== flash attention, swapped-operand 32x32, 2-deep pipeline ========
// r7: template<V> ablation build.  V0=full  V1=noSM  V2=noPV  V3=noQK
// V4=stage-only.  Keep-alives per rule #17; deltas read within-probe.

static __device__ __forceinline__ void qk_tile(const char* lk,
                                               const bf16x8 (&qf)[4],
                                               f32x16 (&S)[2], int l31, int hi) {
#pragma unroll
  for (int i = 0; i < 2; ++i)
#pragma unroll
    for (int r = 0; r < 16; ++r) S[i][r] = 0.f;
  __builtin_amdgcn_s_setprio(1);
#pragma unroll
  for (int d = 0; d < 4; ++d) {
#pragma unroll
    for (int kvt = 0; kvt < 2; ++kvt) {
      int kv = kvt * 32 + l31;
      int a = (kv * 128 + d * 32 + hi * 16) ^ ((kv & 7) << 4);
      bf16x8 kf = *reinterpret_cast<const bf16x8*>(lk + a);
      S[kvt] = MFMA32(kf, qf[d], S[kvt], 0, 0, 0);
    }
  }
  __builtin_amdgcn_s_setprio(0);
}

template <bool DSM, bool DPK, bool DPV>
static __device__ __forceinline__ void sm_pv(const char* lv, f32x16 (&SA)[2],
                                             f32x16 (&Oacc)[2], float& m,
                                             float& lsum, int l31, int hi) {
  if constexpr (DSM) {
    float mt[16];
#pragma unroll
    for (int r = 0; r < 16; ++r) mt[r] = fmaxf(SA[0][r], SA[1][r]);
#pragma unroll
    for (int d = 8; d >= 1; d >>= 1)
#pragma unroll
      for (int r = 0; r < d; ++r) mt[r] = fmaxf(mt[r], mt[r + d]);
    float pmax = fmaxf(mt[0], __shfl_xor(mt[0], 32));

    if (__any(pmax > m + 6.0f)) {  // defer-max: P bounded by 2^6
      float mn = fmaxf(m, pmax);
      float sc = exp2f(m - mn);
      m = mn;
      lsum *= sc;
#pragma unroll
      for (int i = 0; i < 2; ++i)
#pragma unroll
        for (int r = 0; r < 16; ++r) Oacc[i][r] *= sc;
    }

#pragma unroll
    for (int kvt = 0; kvt < 2; ++kvt)
#pragma unroll
      for (int r = 0; r < 16; ++r) SA[kvt][r] = exp2f(SA[kvt][r] - m);

    {
      float st[16];
#pragma unroll
      for (int r = 0; r < 16; ++r) st[r] = SA[0][r] + SA[1][r];
#pragma unroll
      for (int d = 8; d >= 1; d >>= 1)
#pragma unroll
        for (int r = 0; r < d; ++r) st[r] += st[r + d];
      lsum += st[0];
    }
  }

  bf16x8 pfrag[4];
  if constexpr (DPK) {
#pragma unroll
    for (int kvt = 0; kvt < 2; ++kvt)
#pragma unroll
      for (int s1 = 0; s1 < 2; ++s1) {
        u32 X0, X1, Y0, Y1;
        const int c0 = s1 * 8, c1 = c0 + 4;
        asm("v_cvt_pk_bf16_f32 %0, %1, %2"
            : "=v"(X0) : "v"(SA[kvt][c0 + 0]), "v"(SA[kvt][c0 + 1]));
        asm("v_cvt_pk_bf16_f32 %0, %1, %2"
            : "=v"(X1) : "v"(SA[kvt][c0 + 2]), "v"(SA[kvt][c0 + 3]));
        asm("v_cvt_pk_bf16_f32 %0, %1, %2"
            : "=v"(Y0) : "v"(SA[kvt][c1 + 0]), "v"(SA[kvt][c1 + 1]));
        asm("v_cvt_pk_bf16_f32 %0, %1, %2"
            : "=v"(Y1) : "v"(SA[kvt][c1 + 2]), "v"(SA[kvt][c1 + 3]));
        asm("v_permlane32_swap_b32 %0, %1" : "+v"(X0), "+v"(Y0));
        asm("v_permlane32_swap_b32 %0, %1" : "+v"(X1), "+v"(Y1));
        union { u32 w[4]; bf16x8 v; } u;
        u.w[0] = X0; u.w[1] = X1; u.w[2] = Y0; u.w[3] = Y1;
        pfrag[kvt * 2 + s1] = u.v;
        if constexpr (!DPV) {  // noPV: keep pack results live
          keep(u.w[0]); keep(u.w[1]); keep(u.w[2]); keep(u.w[3]);
        }
      }
  }

  if constexpr (DPV) {
    __builtin_amdgcn_s_setprio(1);
#pragma unroll
    for (int s = 0; s < 4; ++s) {
#pragma unroll
      for (int dt = 0; dt < 2; ++dt) {
        int d = dt * 32 + l31;
        int a = (d * 128 + s * 32 + hi * 16) ^ ((d & 7) << 4);
        bf16x8 vf = *reinterpret_cast<const bf16x8*>(lv + a);
        Oacc[dt] = MFMA32(vf, pfrag[s], Oacc[dt], 0, 0, 0);
      }
    }
    __builtin_amdgcn_s_setprio(0);
  }
}

template <int V>
static __device__ __forceinline__ void attn_body(const u16* __restrict__ Q,
                                                 const u16* __restrict__ Kg,
                                                 const u16* __restrict__ VTg,
                                                 u16* __restrict__ O) {
  constexpr bool DO_QK = (V != 3 && V != 4);
  constexpr bool DO_SM = (V != 1 && V != 4);
  constexpr bool DO_PACK = (V != 4);
  constexpr bool DO_PV = (V != 2 && V != 4);
  constexpr int S = 2048, NT = 32;
  __shared__ char lds[4][16384];  // [buf][ K 64x64 bf16 | V^T 64x64 bf16 ]
  const int t = threadIdx.x, wv = t >> 6, lane = t & 63;
  const int bid = blockIdx.x;
  const int slot = bid >> 3;
  const int bh = (bid & 7) * 4 + (slot >> 4);
  const int qb = slot & 15;
  const int b = bh >> 4, h = bh & 15;
  const int q0 = qb * 128 + wv * 32;
  const size_t kbase = (size_t)bh * (S * 64);
  const int l31 = lane & 31, hi = lane >> 5;

  bf16x8 qf[4];
  {
    const u16* qp = Q + kbase + (size_t)(q0 + l31) * 64 + hi * 8;
#pragma unroll
    for (int d = 0; d < 4; ++d)
      qf[d] = *reinterpret_cast<const bf16x8*>(qp + d * 16);
  }
  if constexpr (!DO_QK) {  // keep Q loads live when QK removed
#pragma unroll
    for (int d = 0; d < 4; ++d) {
      union { bf16x8 v; u32 w[4]; } uu; uu.v = qf[d];
      keep(uu.w[0]); keep(uu.w[1]); keep(uu.w[2]); keep(uu.w[3]);
    }
  }

  f32x16 Oacc[2];
#pragma unroll
  for (int i = 0; i < 2; ++i)
#pragma unroll
    for (int r = 0; r < 16; ++r) Oacc[i][r] = 0.f;
  float m = -__builtin_inff(), lsum = 0.f;

  const char* gk0 = (const char*)(Kg + kbase);
  const char* gv0 = (const char*)(VTg + kbase);

#define STAGE(KT, BUF)                                                         \
  {                                                                            \
    char* lk_ = lds[BUF];                                                      \
    const char* gk_ = gk0 + (size_t)(KT) * 8192;                               \
    _Pragma("unroll") for (int c_ = 0; c_ < 2; ++c_) {                         \
      int o_ = (c_ * 256 + t) * 16;                                            \
      int row_ = o_ >> 7, colb_ = o_ & 127;                                    \
      int swz_ = colb_ ^ ((row_ & 7) << 4);                                    \
      load_lds16(gk_ + row_ * 128 + swz_, lk_ + o_);                           \
      load_lds16(gv0 + (size_t)row_ * 4096 + (KT) * 128 + swz_,                \
                 lk_ + 8192 + o_);                                             \
    }                                                                          \
  }

#define HALF(T, SA, SB)                                                        \
  {                                                                            \
    asm volatile("s_waitcnt vmcnt(4)" ::: "memory");                           \
    __builtin_amdgcn_s_barrier();                                              \
    int st_ = (T) + 3 < NT ? (T) + 3 : NT - 1;                                 \
    STAGE(st_, ((T) + 3) & 3)                                                  \
    if constexpr (DO_QK) {                                                     \
      if ((T) + 1 < NT) qk_tile(lds[((T) + 1) & 3], qf, SB, l31, hi);          \
    }                                                                          \
    if constexpr (V != 4)                                                      \
      sm_pv<DO_SM, DO_PACK, DO_PV>(lds[(T) & 3] + 8192, SA, Oacc, m, lsum,     \
                                   l31, hi);                                   \
  }

  f32x16 SaA[2], SaB[2];
#pragma unroll
  for (int i = 0; i < 2; ++i)
#pragma unroll
    for (int r = 0; r < 16; ++r) { SaA[i][r] = 0.f; SaB[i][r] = 0.f; }

  STAGE(0, 0)
  STAGE(1, 1)
  STAGE(2, 2)
  asm volatile("s_waitcnt vmcnt(8)" ::: "memory");  // tile0 landed
  __builtin_amdgcn_s_barrier();
  if constexpr (DO_QK) qk_tile(lds[0], qf, SaA, l31, hi);

  for (int u = 0; u < 16; ++u) {
    const int t0 = 2 * u;
    HALF(t0, SaA, SaB)
    HALF(t0 + 1, SaB, SaA)
  }
#undef HALF
#undef STAGE

  const float lfull = lsum + __shfl_xor(lsum, 32);
  const float rdiv = 1.0f / lfull;
  const int srow = q0 + l31;
  u16* orow = O + (size_t)(b * S + srow) * 1024 + h * 64;
#pragma unroll
  for (int dt = 0; dt < 2; ++dt)
#pragma unroll
    for (int c = 0; c < 4; ++c) {
      float v0 = Oacc[dt][4 * c + 0] * rdiv;
      float v1 = Oacc[dt][4 * c + 1] * rdiv;
      float v2 = Oacc[dt][4 * c + 2] * rdiv;
      float v3 = Oacc[dt][4 * c + 3] * rdiv;
      uint2 pk;
      pk.x = (u32)f2bf(v0) | ((u32)f2bf(v1) << 16);
      pk.y = (u32)f2bf(v2) | ((u32)f2bf(v3) << 16);
      *reinterpret_cast<uint2*>(orow + dt * 32 + c * 8 + hi * 4) = pk;
    }
}

__global__ __launch_bounds__(256) void attn_fwd2(const u16* __restrict__ Q,
                                                 const u16* __restrict__ Kg,
                                                 const u16* __restrict__ VTg,
                                                 u16* __restrict__ O) {
  attn_body<0>(Q, Kg, VTg, O);
}
__global__ __launch_bounds__(256) void attn_ab1(const u16* __restrict__ Q,
                                                const u16* __restrict__ Kg,
                                                const u16* __restrict__ VTg,
                                                u16* __restrict__ O) {
  attn_body<1>(Q, Kg, VTg, O);
}
__global__ __launch_bounds__(256) void attn_ab2(const u16* __restrict__ Q,
                                                const u16* __restrict__ Kg,
                                                const u16* __restrict__ VTg,
                                                u16* __restrict__ O) {
  attn_body<2>(Q, Kg, VTg, O);
}
__global__ __launch_bounds__(256) void attn_ab3(const u16* __restrict__ Q,
                                                const u16* __restrict__ Kg,
                                                const u16* __restrict__ VTg,
                                                u16* __restrict__ O) {
  attn_body<3>(Q, Kg, VTg, O);
}
__global__ __launch_bounds__(256) void attn_ab4(const u16* __restrict__ Q,
                                                const u16* __restrict__ Kg,
                                                const u16* __restrict__ VTg,
                                                u16* __restrict__ O) {
  attn_body<4>(Q, Kg, VTg, O);
}

extern "C" void kernel_launch(void* const* d_in, const int* in_sizes, int n_in,
                              void* d_out, int out_size, void* d_ws, size_t ws_size,
                              hipStream_t stream) {
  (void)in_sizes; (void)n_in; (void)out_size; (void)ws_size;
  const float* x = (const float*)d_in[0];
  const float* wqkv = (const float*)d_in[1];
  const float* wout = (const float*)d_in[2];
  const int* pos = (const int*)d_in[3];
  float* out = (float*)d_out;

  char* ws = (char*)d_ws;
  u16* xb     = (u16*)(ws);             // 8 MB   x bf16 [4096][1024]
  u16* wqkvb  = (u16*)(ws + 8388608);   // 6 MB   Wqkv bf16 [3072][1024]
  u16* woutb  = (u16*)(ws + 14680064);  // 2 MB   Wout bf16 [1024][1024]
  u16* qkvb   = (u16*)(ws + 16777216);  // 24 MB  qkv bf16 / ablation dump
  u16* qro    = (u16*)(ws + 41943040);  // 8 MB   q roped*0.125*log2e
  u16* kro    = (u16*)(ws + 50331648);  // 8 MB   k roped [BH][S][64]
  u16* vt     = (u16*)(ws + 58720256);  // 8 MB   v^T [BH][64][S]
  u16* attno  = (u16*)(ws + 67108864);  // 8 MB   attn out bf16 [4096][1024]
  float2* tab = (float2*)(ws + 75497472); // 512 KB trig table

  cvt_bf16<<<4096, 256, 0, stream>>>(x, xb, 1048576);
  cvt_bf16<<<3072, 256, 0, stream>>>(wqkv, wqkvb, 786432);
  cvt_bf16<<<1024, 256, 0, stream>>>(wout, woutb, 262144);
  build_trig<<<256, 256, 0, stream>>>(pos, tab);
  gemm_bt<true><<<dim3(24, 32), 256, 0, stream>>>(xb, wqkvb, qkvb, 4096, 3072, 1024);
  rope_repack<<<8192, 256, 0, stream>>>(qkvb, tab, qro, kro);
  v_transpose<<<dim3(32, 32), 256, 0, stream>>>(qkvb, vt);
  attn_fwd2<<<512, 256, 0, stream>>>(qro, kro, vt, attno);
  gemm_bt<false><<<dim3(8, 32), 256, 0, stream>>>(attno, woutb, out, 4096, 1024, 1024);
  // ---- diagnostic ablation dispatches (outputs dead; after d_out final) ----
  attn_ab1<<<512, 256, 0, stream>>>(qro, kro, vt, qkvb);
  attn_ab2<<<512, 256, 0, stream>>>(qro, kro, vt, qkvb);
  attn_ab3<<<512, 256, 0, stream>>>(qro, kro, vt, qkvb);
  attn_ab4<<<512, 256, 0, stream>>>(qro, kro, vt, qkvb);
}

// Round 9
// 224.109 us; speedup vs baseline: 1.7326x; 1.7326x over previous
//
#include <hip/hip_runtime.h>
#include <stdint.h>

typedef unsigned short u16;
typedef unsigned int u32;
typedef __bf16 bf16x8 __attribute__((ext_vector_type(8)));
typedef float f32x4 __attribute__((ext_vector_type(4)));
typedef float f32x16 __attribute__((ext_vector_type(16)));

#define MFMA16 __builtin_amdgcn_mfma_f32_16x16x32_bf16
#define MFMA32 __builtin_amdgcn_mfma_f32_32x32x16_bf16

static __device__ __forceinline__ u16 f2bf(float f) {
  union { float f; u32 u; } v; v.f = f;
  u32 r = v.u + 0x7FFFu + ((v.u >> 16) & 1u);
  return (u16)(r >> 16);
}
static __device__ __forceinline__ float bf2f(u16 b) {
  union { float f; u32 u; } v; v.u = ((u32)b) << 16;
  return v.f;
}
static __device__ __forceinline__ void load_lds16(const void* g, void* l) {
  __builtin_amdgcn_global_load_lds(
      (const __attribute__((address_space(1))) void*)g,
      (__attribute__((address_space(3))) void*)l, 16, 0, 0);
}

// ---------------- fp32 -> bf16 convert (vectorized) ----------------
__global__ __launch_bounds__(256) void cvt_bf16(const float* __restrict__ in,
                                                u16* __restrict__ out, int n4) {
  int i = blockIdx.x * 256 + threadIdx.x;
  if (i >= n4) return;
  float4 v = reinterpret_cast<const float4*>(in)[i];
  uint2 r;
  r.x = (u32)f2bf(v.x) | ((u32)f2bf(v.y) << 16);
  r.y = (u32)f2bf(v.z) | ((u32)f2bf(v.w) << 16);
  reinterpret_cast<uint2*>(out)[i] = r;
}

// ---------------- bf16 GEMM, C[M][N] = A[M][K] @ B[N][K]^T ----------------
template <bool OUT_BF16>
__global__ __launch_bounds__(256, 2) void gemm_bt(const u16* __restrict__ A,
                                                  const u16* __restrict__ B,
                                                  void* __restrict__ Cv,
                                                  int M, int N, int K) {
  __shared__ u16 As[128 * 32];
  __shared__ u16 Bs[128 * 32];
  const int t = threadIdx.x;
  const int w = t >> 6, lane = t & 63;
  const int brow = blockIdx.y * 128, bcol = blockIdx.x * 128;
  const int wr = (w >> 1) * 64, wc = (w & 1) * 64;

  f32x4 acc[4][4];
#pragma unroll
  for (int i = 0; i < 4; ++i)
#pragma unroll
    for (int j = 0; j < 4; ++j) acc[i][j] = (f32x4){0.f, 0.f, 0.f, 0.f};

  const int srow = w * 16 + (lane >> 2);
  const int scol = (lane & 3) * 8;
  const u16* ga = A + (size_t)(brow + srow) * K + scol;
  const u16* gb = B + (size_t)(bcol + srow) * K + scol;
  const size_t rstep = (size_t)64 * K;
  u16* ldsA = As + w * 512;
  u16* ldsB = Bs + w * 512;

  const int lc = lane & 15, lg = lane >> 4;
  const int kg = lg * 8;

  const int nk = K >> 5;
  for (int kt = 0; kt < nk; ++kt) {
    __syncthreads();
    load_lds16(ga, ldsA);
    load_lds16(ga + rstep, (char*)ldsA + 4096);
    load_lds16(gb, ldsB);
    load_lds16(gb + rstep, (char*)ldsB + 4096);
    ga += 32; gb += 32;
    asm volatile("s_waitcnt vmcnt(0)" ::: "memory");
    __syncthreads();
    bf16x8 af[4], bfr[4];
#pragma unroll
    for (int i = 0; i < 4; ++i)
      af[i] = *reinterpret_cast<const bf16x8*>(As + (wr + i * 16 + lc) * 32 + kg);
#pragma unroll
    for (int j = 0; j < 4; ++j)
      bfr[j] = *reinterpret_cast<const bf16x8*>(Bs + (wc + j * 16 + lc) * 32 + kg);
#pragma unroll
    for (int i = 0; i < 4; ++i)
#pragma unroll
      for (int j = 0; j < 4; ++j)
        acc[i][j] = MFMA16(af[i], bfr[j], acc[i][j], 0, 0, 0);
  }

  const int r0 = lg * 4;
#pragma unroll
  for (int i = 0; i < 4; ++i)
#pragma unroll
    for (int j = 0; j < 4; ++j)
#pragma unroll
      for (int r = 0; r < 4; ++r) {
        const int m = brow + wr + i * 16 + r0 + r;
        const int n = bcol + wc + j * 16 + lc;
        if constexpr (OUT_BF16)
          ((u16*)Cv)[(size_t)m * N + n] = f2bf(acc[i][j][r]);
        else
          ((float*)Cv)[(size_t)m * N + n] = acc[i][j][r];
      }
}

// ---------------- RoPE trig table: [s][pair] -> (cos, sin) ----------------
__global__ __launch_bounds__(256) void build_trig(const int* __restrict__ pos,
                                                  float2* __restrict__ tab) {
  int i = blockIdx.x * 256 + threadIdx.x;
  int s = i >> 5, p = i & 31;
  float inv = powf(10000.0f, -(float)p * (1.0f / 32.0f));
  float fr = (float)pos[s] * inv;
  float sn, cs;
  sincosf(fr, &sn, &cs);
  tab[i] = make_float2(cs, sn);
}

// ------- RoPE + repack q,k -> [B*H][S][64]  (q pre-scaled 0.125*log2e) -----
__global__ __launch_bounds__(256) void rope_repack(const u16* __restrict__ qkv,
                                                   const float2* __restrict__ tab,
                                                   u16* __restrict__ Qro,
                                                   u16* __restrict__ Kro) {
  int idx = blockIdx.x * 256 + threadIdx.x;
  int p = idx & 31;
  int h = (idx >> 5) & 15;
  int m = idx >> 9;
  int b = m >> 11, s = m & 2047;
  const u32* row = reinterpret_cast<const u32*>(qkv + (size_t)m * 3072);
  u32 qp = row[h * 32 + p];
  u32 kp = row[512 + h * 32 + p];
  float2 cssn = tab[s * 32 + p];
  float cs = cssn.x, sn = cssn.y;
  float qe = bf2f((u16)(qp & 0xffffu)), qo = bf2f((u16)(qp >> 16));
  float ke = bf2f((u16)(kp & 0xffffu)), ko = bf2f((u16)(kp >> 16));
  const float QS = 0.18033688011112042f;  // 0.125 * log2(e)
  float qre = (qe * cs - qo * sn) * QS;
  float qro_ = (qe * sn + qo * cs) * QS;
  float kre = ke * cs - ko * sn;
  float kro_ = ke * sn + ko * cs;
  size_t o = ((size_t)(b * 16 + h) * 2048 + s) * 32 + p;
  reinterpret_cast<u32*>(Qro)[o] = (u32)f2bf(qre) | ((u32)f2bf(qro_) << 16);
  reinterpret_cast<u32*>(Kro)[o] = (u32)f2bf(kre) | ((u32)f2bf(kro_) << 16);
}

// ---------------- V -> V^T   ([B*H][S][64] slice of qkv -> [B*H][64][S]) ----
__global__ __launch_bounds__(256) void v_transpose(const u16* __restrict__ qkv,
                                                   u16* __restrict__ VT) {
  const int bh = blockIdx.y;
  const int s0 = blockIdx.x * 64;
  const int b = bh >> 4, h = bh & 15;
  __shared__ u16 tile[64][72];
  const int t = threadIdx.x;
#pragma unroll
  for (int c = 0; c < 2; ++c) {
    int r = c * 32 + (t >> 3);
    int d = (t & 7) * 8;
    const u16* src = qkv + (size_t)(b * 2048 + s0 + r) * 3072 + 2048 + h * 64 + d;
    *reinterpret_cast<uint4*>(&tile[r][d]) = *reinterpret_cast<const uint4*>(src);
  }
  __syncthreads();
#pragma unroll
  for (int c = 0; c < 2; ++c) {
    int dd = c * 32 + (t >> 3);
    int sg = (t & 7) * 8;
    u16 tmp[8];
#pragma unroll
    for (int jj = 0; jj < 8; ++jj) tmp[jj] = tile[sg + jj][dd];
    *reinterpret_cast<uint4*>(VT + ((size_t)bh * 64 + dd) * 2048 + s0 + sg) =
        *reinterpret_cast<const uint4*>(tmp);
  }
}

// ======== flash attention, swapped 32x32, 2-way KV-SPLIT (r8) ========
// Occupancy regime test: grid 1024, LDS 32KB (2 bufs), launch_bounds(256,4)
// -> 4 blocks/CU, 16 waves/CU (4/SIMD), 2x previous. Each block: 128 q-rows
// x half the KV (NT=16). Writes unnormalized bf16 partials + (l,m) stats;
// attn_merge combines exactly (log-sum-exp).

static __device__ __forceinline__ void qk_tile(const char* lk,
                                               const bf16x8 (&qf)[4],
                                               f32x16 (&S)[2], int l31, int hi) {
#pragma unroll
  for (int i = 0; i < 2; ++i)
#pragma unroll
    for (int r = 0; r < 16; ++r) S[i][r] = 0.f;
  __builtin_amdgcn_s_setprio(1);
#pragma unroll
  for (int d = 0; d < 4; ++d) {
#pragma unroll
    for (int kvt = 0; kvt < 2; ++kvt) {
      int kv = kvt * 32 + l31;
      int a = (kv * 128 + d * 32 + hi * 16) ^ ((kv & 7) << 4);
      bf16x8 kf = *reinterpret_cast<const bf16x8*>(lk + a);
      S[kvt] = MFMA32(kf, qf[d], S[kvt], 0, 0, 0);
    }
  }
  __builtin_amdgcn_s_setprio(0);
}

static __device__ __forceinline__ void sm_pv(const char* lv, f32x16 (&SA)[2],
                                             f32x16 (&Oacc)[2], float& m,
                                             float& lsum, int l31, int hi) {
  float mt[16];
#pragma unroll
  for (int r = 0; r < 16; ++r) mt[r] = fmaxf(SA[0][r], SA[1][r]);
#pragma unroll
  for (int d = 8; d >= 1; d >>= 1)
#pragma unroll
    for (int r = 0; r < d; ++r) mt[r] = fmaxf(mt[r], mt[r + d]);
  float pmax = fmaxf(mt[0], __shfl_xor(mt[0], 32));

  if (__any(pmax > m + 6.0f)) {  // defer-max: P bounded by 2^6
    float mn = fmaxf(m, pmax);
    float sc = exp2f(m - mn);
    m = mn;
    lsum *= sc;
#pragma unroll
    for (int i = 0; i < 2; ++i)
#pragma unroll
      for (int r = 0; r < 16; ++r) Oacc[i][r] *= sc;
  }

#pragma unroll
  for (int kvt = 0; kvt < 2; ++kvt)
#pragma unroll
    for (int r = 0; r < 16; ++r) SA[kvt][r] = exp2f(SA[kvt][r] - m);

  {
    float st[16];
#pragma unroll
    for (int r = 0; r < 16; ++r) st[r] = SA[0][r] + SA[1][r];
#pragma unroll
    for (int d = 8; d >= 1; d >>= 1)
#pragma unroll
      for (int r = 0; r < d; ++r) st[r] += st[r + d];
    lsum += st[0];
  }

  bf16x8 pfrag[4];
#pragma unroll
  for (int kvt = 0; kvt < 2; ++kvt)
#pragma unroll
    for (int s1 = 0; s1 < 2; ++s1) {
      u32 X0, X1, Y0, Y1;
      const int c0 = s1 * 8, c1 = c0 + 4;
      asm("v_cvt_pk_bf16_f32 %0, %1, %2"
          : "=v"(X0) : "v"(SA[kvt][c0 + 0]), "v"(SA[kvt][c0 + 1]));
      asm("v_cvt_pk_bf16_f32 %0, %1, %2"
          : "=v"(X1) : "v"(SA[kvt][c0 + 2]), "v"(SA[kvt][c0 + 3]));
      asm("v_cvt_pk_bf16_f32 %0, %1, %2"
          : "=v"(Y0) : "v"(SA[kvt][c1 + 0]), "v"(SA[kvt][c1 + 1]));
      asm("v_cvt_pk_bf16_f32 %0, %1, %2"
          : "=v"(Y1) : "v"(SA[kvt][c1 + 2]), "v"(SA[kvt][c1 + 3]));
      asm("v_permlane32_swap_b32 %0, %1" : "+v"(X0), "+v"(Y0));
      asm("v_permlane32_swap_b32 %0, %1" : "+v"(X1), "+v"(Y1));
      union { u32 w[4]; bf16x8 v; } u;
      u.w[0] = X0; u.w[1] = X1; u.w[2] = Y0; u.w[3] = Y1;
      pfrag[kvt * 2 + s1] = u.v;
    }

  __builtin_amdgcn_s_setprio(1);
#pragma unroll
  for (int s = 0; s < 4; ++s) {
#pragma unroll
    for (int dt = 0; dt < 2; ++dt) {
      int d = dt * 32 + l31;
      int a = (d * 128 + s * 32 + hi * 16) ^ ((d & 7) << 4);
      bf16x8 vf = *reinterpret_cast<const bf16x8*>(lv + a);
      Oacc[dt] = MFMA32(vf, pfrag[s], Oacc[dt], 0, 0, 0);
    }
  }
  __builtin_amdgcn_s_setprio(0);
}

__global__ __launch_bounds__(256, 4) void attn_split(const u16* __restrict__ Q,
                                                     const u16* __restrict__ Kg,
                                                     const u16* __restrict__ VTg,
                                                     u16* __restrict__ part,
                                                     float2* __restrict__ stats) {
  constexpr int S = 2048, NT = 16;
  __shared__ char lds[2][16384];  // [buf][ K 64x64 bf16 | V^T 64x64 bf16 ]
  const int t = threadIdx.x, wv = t >> 6, lane = t & 63;
  const int bid = blockIdx.x;  // 1024 blocks
  // XCD grouping: 4 bh per XCD; within: 16 qb x 2 splits
  const int slot = bid >> 3;               // 0..127
  const int bh = (bid & 7) * 4 + (slot >> 5);
  const int rest = slot & 31;
  const int qb = rest >> 1, sp = rest & 1;
  const int q0 = qb * 128 + wv * 32;
  const size_t kbase = (size_t)bh * (S * 64);
  const int l31 = lane & 31, hi = lane >> 5;

  bf16x8 qf[4];
  {
    const u16* qp = Q + kbase + (size_t)(q0 + l31) * 64 + hi * 8;
#pragma unroll
    for (int d = 0; d < 4; ++d)
      qf[d] = *reinterpret_cast<const bf16x8*>(qp + d * 16);
  }

  f32x16 Oacc[2];
#pragma unroll
  for (int i = 0; i < 2; ++i)
#pragma unroll
    for (int r = 0; r < 16; ++r) Oacc[i][r] = 0.f;
  float m = -__builtin_inff(), lsum = 0.f;

  const char* gk0 = (const char*)(Kg + kbase);
  const char* gv0 = (const char*)(VTg + kbase);

  // tile index within split; global tile = sp*16 + KT
#define STAGE(KT, BUF)                                                         \
  {                                                                            \
    char* lk_ = lds[BUF];                                                      \
    const char* gk_ = gk0 + (size_t)(sp * 16 + (KT)) * 8192;                   \
    _Pragma("unroll") for (int c_ = 0; c_ < 2; ++c_) {                         \
      int o_ = (c_ * 256 + t) * 16;                                            \
      int row_ = o_ >> 7, colb_ = o_ & 127;                                    \
      int swz_ = colb_ ^ ((row_ & 7) << 4);                                    \
      load_lds16(gk_ + row_ * 128 + swz_, lk_ + o_);                           \
      load_lds16(gv0 + (size_t)row_ * 4096 + sp * 2048 + (KT) * 128 + swz_,    \
                 lk_ + 8192 + o_);                                             \
    }                                                                          \
  }

  STAGE(0, 0)

  f32x16 Sa[2];
  for (int kt = 0; kt < NT; ++kt) {
    asm volatile("s_waitcnt vmcnt(0)" ::: "memory");
    __builtin_amdgcn_s_barrier();
    if (kt + 1 < NT) STAGE(kt + 1, (kt + 1) & 1)
    const char* lb = lds[kt & 1];
    qk_tile(lb, qf, Sa, l31, hi);
    sm_pv(lb + 8192, Sa, Oacc, m, lsum, l31, hi);
  }
#undef STAGE

  // ---- epilogue: UNNORMALIZED bf16 partial + (l, m) stats ----
  const float lfull = lsum + __shfl_xor(lsum, 32);
  const int srow = q0 + l31;
  const size_t rowi = (size_t)(sp * 32 + bh) * 2048 + srow;
  u16* prow = part + rowi * 64;
#pragma unroll
  for (int dt = 0; dt < 2; ++dt)
#pragma unroll
    for (int c = 0; c < 4; ++c) {
      uint2 pk;
      pk.x = (u32)f2bf(Oacc[dt][4 * c + 0]) | ((u32)f2bf(Oacc[dt][4 * c + 1]) << 16);
      pk.y = (u32)f2bf(Oacc[dt][4 * c + 2]) | ((u32)f2bf(Oacc[dt][4 * c + 3]) << 16);
      *reinterpret_cast<uint2*>(prow + dt * 32 + c * 8 + hi * 4) = pk;
    }
  if (hi == 0) stats[rowi] = make_float2(lfull, m);
}

// ---- merge the two KV-split partials (exact log-sum-exp combine) ----
__global__ __launch_bounds__(256) void attn_merge(const u16* __restrict__ part,
                                                  const float2* __restrict__ stats,
                                                  u16* __restrict__ attno) {
  int idx = blockIdx.x * 256 + threadIdx.x;  // 524288 = 65536 rows x 8 chunks
  int r = idx >> 3, c = idx & 7;
  float2 s0 = stats[r];
  float2 s1 = stats[65536 + r];
  float M = fmaxf(s0.y, s1.y);
  float w0 = exp2f(s0.y - M), w1 = exp2f(s1.y - M);
  float rden = 1.0f / (w0 * s0.x + w1 * s1.x);
  w0 *= rden; w1 *= rden;
  const uint4 a = *reinterpret_cast<const uint4*>(part + (size_t)r * 64 + c * 8);
  const uint4 b4 = *reinterpret_cast<const uint4*>(part + 4194304 + (size_t)r * 64 + c * 8);
  const u32 aw[4] = {a.x, a.y, a.z, a.w}, bw[4] = {b4.x, b4.y, b4.z, b4.w};
  u32 ow[4];
#pragma unroll
  for (int i = 0; i < 4; ++i) {
    float r0 = w0 * bf2f((u16)(aw[i] & 0xffffu)) + w1 * bf2f((u16)(bw[i] & 0xffffu));
    float r1 = w0 * bf2f((u16)(aw[i] >> 16)) + w1 * bf2f((u16)(bw[i] >> 16));
    ow[i] = (u32)f2bf(r0) | ((u32)f2bf(r1) << 16);
  }
  int bh = r >> 11, s = r & 2047;
  int b = bh >> 4, h = bh & 15;
  uint4 o; o.x = ow[0]; o.y = ow[1]; o.z = ow[2]; o.w = ow[3];
  *reinterpret_cast<uint4*>(attno + (size_t)(b * 2048 + s) * 1024 + h * 64 + c * 8) = o;
}

extern "C" void kernel_launch(void* const* d_in, const int* in_sizes, int n_in,
                              void* d_out, int out_size, void* d_ws, size_t ws_size,
                              hipStream_t stream) {
  (void)in_sizes; (void)n_in; (void)out_size; (void)ws_size;
  const float* x = (const float*)d_in[0];
  const float* wqkv = (const float*)d_in[1];
  const float* wout = (const float*)d_in[2];
  const int* pos = (const int*)d_in[3];
  float* out = (float*)d_out;

  char* ws = (char*)d_ws;
  u16* xb     = (u16*)(ws);             // 8 MB   x bf16 [4096][1024]
  u16* wqkvb  = (u16*)(ws + 8388608);   // 6 MB   Wqkv bf16 [3072][1024]
  u16* woutb  = (u16*)(ws + 14680064);  // 2 MB   Wout bf16 [1024][1024]
  u16* qkvb   = (u16*)(ws + 16777216);  // 24 MB  qkv bf16; later: partials+stats
  u16* qro    = (u16*)(ws + 41943040);  // 8 MB   q roped*0.125*log2e
  u16* kro    = (u16*)(ws + 50331648);  // 8 MB   k roped [BH][S][64]
  u16* vt     = (u16*)(ws + 58720256);  // 8 MB   v^T [BH][64][S]
  u16* attno  = (u16*)(ws + 67108864);  // 8 MB   attn out bf16 [4096][1024]
  float2* tab = (float2*)(ws + 75497472); // 512 KB trig table

  // split-attention scratch overlays the dead qkvb region (safe: qkvb's last
  // reader is v_transpose, which runs before attn_split):
  u16* part     = qkvb;                         // 16 MB  [2][32][2048][64] bf16
  float2* stats = (float2*)(ws + 16777216 + 16777216);  // 1 MB [2][65536]

  cvt_bf16<<<4096, 256, 0, stream>>>(x, xb, 1048576);
  cvt_bf16<<<3072, 256, 0, stream>>>(wqkv, wqkvb, 786432);
  cvt_bf16<<<1024, 256, 0, stream>>>(wout, woutb, 262144);
  build_trig<<<256, 256, 0, stream>>>(pos, tab);
  gemm_bt<true><<<dim3(24, 32), 256, 0, stream>>>(xb, wqkvb, qkvb, 4096, 3072, 1024);
  rope_repack<<<8192, 256, 0, stream>>>(qkvb, tab, qro, kro);
  v_transpose<<<dim3(32, 32), 256, 0, stream>>>(qkvb, vt);
  attn_split<<<1024, 256, 0, stream>>>(qro, kro, vt, part, stats);
  attn_merge<<<2048, 256, 0, stream>>>(part, stats, attno);
  gemm_bt<false><<<dim3(8, 32), 256, 0, stream>>>(attno, woutb, out, 4096, 1024, 1024);
}

// Round 10
// 214.992 us; speedup vs baseline: 1.8061x; 1.0424x over previous
//
#include <hip/hip_runtime.h>
#include <stdint.h>

typedef unsigned short u16;
typedef unsigned int u32;
typedef __bf16 bf16x8 __attribute__((ext_vector_type(8)));
typedef float f32x4 __attribute__((ext_vector_type(4)));
typedef float f32x16 __attribute__((ext_vector_type(16)));

#define MFMA16 __builtin_amdgcn_mfma_f32_16x16x32_bf16
#define MFMA32 __builtin_amdgcn_mfma_f32_32x32x16_bf16

static __device__ __forceinline__ u16 f2bf(float f) {
  union { float f; u32 u; } v; v.f = f;
  u32 r = v.u + 0x7FFFu + ((v.u >> 16) & 1u);
  return (u16)(r >> 16);
}
static __device__ __forceinline__ float bf2f(u16 b) {
  union { float f; u32 u; } v; v.u = ((u32)b) << 16;
  return v.f;
}
static __device__ __forceinline__ void load_lds16(const void* g, void* l) {
  __builtin_amdgcn_global_load_lds(
      (const __attribute__((address_space(1))) void*)g,
      (__attribute__((address_space(3))) void*)l, 16, 0, 0);
}

// ------- prep: 3x fp32->bf16 convert + trig table, range-dispatched -------
__global__ __launch_bounds__(256) void prep_fused(const float* __restrict__ x,
                                                  const float* __restrict__ wqkv,
                                                  const float* __restrict__ wout,
                                                  const int* __restrict__ pos,
                                                  u16* __restrict__ xb,
                                                  u16* __restrict__ wqkvb,
                                                  u16* __restrict__ woutb,
                                                  float2* __restrict__ tab) {
  const int blk = blockIdx.x;
  if (blk < 8192) {  // converts: 2097152 float4-quads total
    int i = blk * 256 + threadIdx.x;
    const float* src;
    u16* dst;
    int off;
    if (i < 1048576) { src = x; dst = xb; off = i; }
    else if (i < 1835008) { src = wqkv; dst = wqkvb; off = i - 1048576; }
    else { src = wout; dst = woutb; off = i - 1835008; }
    float4 v = reinterpret_cast<const float4*>(src)[off];
    uint2 r;
    r.x = (u32)f2bf(v.x) | ((u32)f2bf(v.y) << 16);
    r.y = (u32)f2bf(v.z) | ((u32)f2bf(v.w) << 16);
    reinterpret_cast<uint2*>(dst)[off] = r;
  } else {  // trig: 65536 entries
    int i = (blk - 8192) * 256 + threadIdx.x;
    int s = i >> 5, p = i & 31;
    float inv = powf(10000.0f, -(float)p * (1.0f / 32.0f));
    float fr = (float)pos[s] * inv;
    float sn, cs;
    sincosf(fr, &sn, &cs);
    tab[i] = make_float2(cs, sn);
  }
}

// ---- QKV GEMM with fused RoPE epilogue ----
// qkv[m][n] = xb[m][:] . wqkvb[n][:];  n<1024 -> q (roped, *0.125*log2e ->qro)
// 1024<=n<2048 -> k (roped -> kro); n>=2048 -> v (raw -> vpack[m][1024]).
// Region is block-uniform (128-col tiles align with 1024/2048 boundaries).
__global__ __launch_bounds__(256, 2) void gemm_qkv(const u16* __restrict__ A,
                                                   const u16* __restrict__ B,
                                                   const float2* __restrict__ tab,
                                                   u16* __restrict__ qro,
                                                   u16* __restrict__ kro,
                                                   u16* __restrict__ vpack) {
  constexpr int K = 1024;
  __shared__ u16 As[128 * 32];
  __shared__ u16 Bs[128 * 32];
  const int t = threadIdx.x;
  const int w = t >> 6, lane = t & 63;
  const int brow = blockIdx.y * 128, bcol = blockIdx.x * 128;
  const int wr = (w >> 1) * 64, wc = (w & 1) * 64;

  f32x4 acc[4][4];
#pragma unroll
  for (int i = 0; i < 4; ++i)
#pragma unroll
    for (int j = 0; j < 4; ++j) acc[i][j] = (f32x4){0.f, 0.f, 0.f, 0.f};

  const int srow = w * 16 + (lane >> 2);
  const int scol = (lane & 3) * 8;
  const u16* ga = A + (size_t)(brow + srow) * K + scol;
  const u16* gb = B + (size_t)(bcol + srow) * K + scol;
  const size_t rstep = (size_t)64 * K;
  u16* ldsA = As + w * 512;
  u16* ldsB = Bs + w * 512;

  const int lc = lane & 15, lg = lane >> 4;
  const int kg = lg * 8;

  for (int kt = 0; kt < K / 32; ++kt) {
    __syncthreads();
    load_lds16(ga, ldsA);
    load_lds16(ga + rstep, (char*)ldsA + 4096);
    load_lds16(gb, ldsB);
    load_lds16(gb + rstep, (char*)ldsB + 4096);
    ga += 32; gb += 32;
    asm volatile("s_waitcnt vmcnt(0)" ::: "memory");
    __syncthreads();
    bf16x8 af[4], bfr[4];
#pragma unroll
    for (int i = 0; i < 4; ++i)
      af[i] = *reinterpret_cast<const bf16x8*>(As + (wr + i * 16 + lc) * 32 + kg);
#pragma unroll
    for (int j = 0; j < 4; ++j)
      bfr[j] = *reinterpret_cast<const bf16x8*>(Bs + (wc + j * 16 + lc) * 32 + kg);
#pragma unroll
    for (int i = 0; i < 4; ++i)
#pragma unroll
      for (int j = 0; j < 4; ++j)
        acc[i][j] = MFMA16(af[i], bfr[j], acc[i][j], 0, 0, 0);
  }

  const int r0 = lg * 4;
  if (bcol >= 2048) {
    // ---- V region: raw bf16 into vpack[m][n-2048] ----
#pragma unroll
    for (int i = 0; i < 4; ++i)
#pragma unroll
      for (int j = 0; j < 4; ++j)
#pragma unroll
        for (int r = 0; r < 4; ++r) {
          const int m = brow + wr + i * 16 + r0 + r;
          const int n = bcol + wc + j * 16 + lc;
          vpack[(size_t)m * 1024 + (n - 2048)] = f2bf(acc[i][j][r]);
        }
  } else {
    const bool isq = bcol < 1024;
    u16* dst = isq ? qro : kro;
    const float scale = isq ? 0.18033688011112042f : 1.0f;  // 0.125*log2e
#pragma unroll
    for (int i = 0; i < 4; ++i)
#pragma unroll
      for (int j = 0; j < 4; ++j)
#pragma unroll
        for (int r = 0; r < 4; ++r) {
          const int m = brow + wr + i * 16 + r0 + r;
          const int n = bcol + wc + j * 16 + lc;
          const int nn = n & 1023;
          const int h = nn >> 6, d = nn & 63, p = d >> 1;
          const int s = m & 2047, b = m >> 11;
          float val = acc[i][j][r];
          float pv = __shfl_xor(val, 1);  // partner element of the RoPE pair
          float2 cssn = tab[s * 32 + p];
          float o = (d & 1) ? (pv * cssn.y + val * cssn.x)
                            : (val * cssn.x - pv * cssn.y);
          dst[((size_t)(b * 16 + h) * 2048 + s) * 64 + d] = f2bf(o * scale);
        }
  }
}

// ---------------- output GEMM: C[M][N] = A[M][K] @ B[N][K]^T, fp32 out ----
__global__ __launch_bounds__(256, 2) void gemm_out(const u16* __restrict__ A,
                                                   const u16* __restrict__ B,
                                                   float* __restrict__ C,
                                                   int M, int N, int K) {
  __shared__ u16 As[128 * 32];
  __shared__ u16 Bs[128 * 32];
  const int t = threadIdx.x;
  const int w = t >> 6, lane = t & 63;
  const int brow = blockIdx.y * 128, bcol = blockIdx.x * 128;
  const int wr = (w >> 1) * 64, wc = (w & 1) * 64;

  f32x4 acc[4][4];
#pragma unroll
  for (int i = 0; i < 4; ++i)
#pragma unroll
    for (int j = 0; j < 4; ++j) acc[i][j] = (f32x4){0.f, 0.f, 0.f, 0.f};

  const int srow = w * 16 + (lane >> 2);
  const int scol = (lane & 3) * 8;
  const u16* ga = A + (size_t)(brow + srow) * K + scol;
  const u16* gb = B + (size_t)(bcol + srow) * K + scol;
  const size_t rstep = (size_t)64 * K;
  u16* ldsA = As + w * 512;
  u16* ldsB = Bs + w * 512;

  const int lc = lane & 15, lg = lane >> 4;
  const int kg = lg * 8;

  const int nk = K >> 5;
  for (int kt = 0; kt < nk; ++kt) {
    __syncthreads();
    load_lds16(ga, ldsA);
    load_lds16(ga + rstep, (char*)ldsA + 4096);
    load_lds16(gb, ldsB);
    load_lds16(gb + rstep, (char*)ldsB + 4096);
    ga += 32; gb += 32;
    asm volatile("s_waitcnt vmcnt(0)" ::: "memory");
    __syncthreads();
    bf16x8 af[4], bfr[4];
#pragma unroll
    for (int i = 0; i < 4; ++i)
      af[i] = *reinterpret_cast<const bf16x8*>(As + (wr + i * 16 + lc) * 32 + kg);
#pragma unroll
    for (int j = 0; j < 4; ++j)
      bfr[j] = *reinterpret_cast<const bf16x8*>(Bs + (wc + j * 16 + lc) * 32 + kg);
#pragma unroll
    for (int i = 0; i < 4; ++i)
#pragma unroll
      for (int j = 0; j < 4; ++j)
        acc[i][j] = MFMA16(af[i], bfr[j], acc[i][j], 0, 0, 0);
  }

  const int r0 = lg * 4;
#pragma unroll
  for (int i = 0; i < 4; ++i)
#pragma unroll
    for (int j = 0; j < 4; ++j)
#pragma unroll
      for (int r = 0; r < 4; ++r) {
        const int m = brow + wr + i * 16 + r0 + r;
        const int n = bcol + wc + j * 16 + lc;
        C[(size_t)m * N + n] = acc[i][j][r];
      }
}

// ---------------- V -> V^T   (vpack[B*S][1024] -> [B*H][64][S]) ----
__global__ __launch_bounds__(256) void v_transpose(const u16* __restrict__ vpack,
                                                   u16* __restrict__ VT) {
  const int bh = blockIdx.y;
  const int s0 = blockIdx.x * 64;
  const int b = bh >> 4, h = bh & 15;
  __shared__ u16 tile[64][72];
  const int t = threadIdx.x;
#pragma unroll
  for (int c = 0; c < 2; ++c) {
    int r = c * 32 + (t >> 3);
    int d = (t & 7) * 8;
    const u16* src = vpack + (size_t)(b * 2048 + s0 + r) * 1024 + h * 64 + d;
    *reinterpret_cast<uint4*>(&tile[r][d]) = *reinterpret_cast<const uint4*>(src);
  }
  __syncthreads();
#pragma unroll
  for (int c = 0; c < 2; ++c) {
    int dd = c * 32 + (t >> 3);
    int sg = (t & 7) * 8;
    u16 tmp[8];
#pragma unroll
    for (int jj = 0; jj < 8; ++jj) tmp[jj] = tile[sg + jj][dd];
    *reinterpret_cast<uint4*>(VT + ((size_t)bh * 64 + dd) * 2048 + s0 + sg) =
        *reinterpret_cast<const uint4*>(tmp);
  }
}

// ======== flash attention, swapped 32x32, 2-way KV-SPLIT (unchanged r8) ====
static __device__ __forceinline__ void qk_tile(const char* lk,
                                               const bf16x8 (&qf)[4],
                                               f32x16 (&S)[2], int l31, int hi) {
#pragma unroll
  for (int i = 0; i < 2; ++i)
#pragma unroll
    for (int r = 0; r < 16; ++r) S[i][r] = 0.f;
  __builtin_amdgcn_s_setprio(1);
#pragma unroll
  for (int d = 0; d < 4; ++d) {
#pragma unroll
    for (int kvt = 0; kvt < 2; ++kvt) {
      int kv = kvt * 32 + l31;
      int a = (kv * 128 + d * 32 + hi * 16) ^ ((kv & 7) << 4);
      bf16x8 kf = *reinterpret_cast<const bf16x8*>(lk + a);
      S[kvt] = MFMA32(kf, qf[d], S[kvt], 0, 0, 0);
    }
  }
  __builtin_amdgcn_s_setprio(0);
}

static __device__ __forceinline__ void sm_pv(const char* lv, f32x16 (&SA)[2],
                                             f32x16 (&Oacc)[2], float& m,
                                             float& lsum, int l31, int hi) {
  float mt[16];
#pragma unroll
  for (int r = 0; r < 16; ++r) mt[r] = fmaxf(SA[0][r], SA[1][r]);
#pragma unroll
  for (int d = 8; d >= 1; d >>= 1)
#pragma unroll
    for (int r = 0; r < d; ++r) mt[r] = fmaxf(mt[r], mt[r + d]);
  float pmax = fmaxf(mt[0], __shfl_xor(mt[0], 32));

  if (__any(pmax > m + 6.0f)) {  // defer-max: P bounded by 2^6
    float mn = fmaxf(m, pmax);
    float sc = exp2f(m - mn);
    m = mn;
    lsum *= sc;
#pragma unroll
    for (int i = 0; i < 2; ++i)
#pragma unroll
      for (int r = 0; r < 16; ++r) Oacc[i][r] *= sc;
  }

#pragma unroll
  for (int kvt = 0; kvt < 2; ++kvt)
#pragma unroll
    for (int r = 0; r < 16; ++r) SA[kvt][r] = exp2f(SA[kvt][r] - m);

  {
    float st[16];
#pragma unroll
    for (int r = 0; r < 16; ++r) st[r] = SA[0][r] + SA[1][r];
#pragma unroll
    for (int d = 8; d >= 1; d >>= 1)
#pragma unroll
      for (int r = 0; r < d; ++r) st[r] += st[r + d];
    lsum += st[0];
  }

  bf16x8 pfrag[4];
#pragma unroll
  for (int kvt = 0; kvt < 2; ++kvt)
#pragma unroll
    for (int s1 = 0; s1 < 2; ++s1) {
      u32 X0, X1, Y0, Y1;
      const int c0 = s1 * 8, c1 = c0 + 4;
      asm("v_cvt_pk_bf16_f32 %0, %1, %2"
          : "=v"(X0) : "v"(SA[kvt][c0 + 0]), "v"(SA[kvt][c0 + 1]));
      asm("v_cvt_pk_bf16_f32 %0, %1, %2"
          : "=v"(X1) : "v"(SA[kvt][c0 + 2]), "v"(SA[kvt][c0 + 3]));
      asm("v_cvt_pk_bf16_f32 %0, %1, %2"
          : "=v"(Y0) : "v"(SA[kvt][c1 + 0]), "v"(SA[kvt][c1 + 1]));
      asm("v_cvt_pk_bf16_f32 %0, %1, %2"
          : "=v"(Y1) : "v"(SA[kvt][c1 + 2]), "v"(SA[kvt][c1 + 3]));
      asm("v_permlane32_swap_b32 %0, %1" : "+v"(X0), "+v"(Y0));
      asm("v_permlane32_swap_b32 %0, %1" : "+v"(X1), "+v"(Y1));
      union { u32 w[4]; bf16x8 v; } u;
      u.w[0] = X0; u.w[1] = X1; u.w[2] = Y0; u.w[3] = Y1;
      pfrag[kvt * 2 + s1] = u.v;
    }

  __builtin_amdgcn_s_setprio(1);
#pragma unroll
  for (int s = 0; s < 4; ++s) {
#pragma unroll
    for (int dt = 0; dt < 2; ++dt) {
      int d = dt * 32 + l31;
      int a = (d * 128 + s * 32 + hi * 16) ^ ((d & 7) << 4);
      bf16x8 vf = *reinterpret_cast<const bf16x8*>(lv + a);
      Oacc[dt] = MFMA32(vf, pfrag[s], Oacc[dt], 0, 0, 0);
    }
  }
  __builtin_amdgcn_s_setprio(0);
}

__global__ __launch_bounds__(256, 4) void attn_split(const u16* __restrict__ Q,
                                                     const u16* __restrict__ Kg,
                                                     const u16* __restrict__ VTg,
                                                     u16* __restrict__ part,
                                                     float2* __restrict__ stats) {
  constexpr int S = 2048, NT = 16;
  __shared__ char lds[2][16384];
  const int t = threadIdx.x, wv = t >> 6, lane = t & 63;
  const int bid = blockIdx.x;  // 1024 blocks
  const int slot = bid >> 3;
  const int bh = (bid & 7) * 4 + (slot >> 5);
  const int rest = slot & 31;
  const int qb = rest >> 1, sp = rest & 1;
  const int q0 = qb * 128 + wv * 32;
  const size_t kbase = (size_t)bh * (S * 64);
  const int l31 = lane & 31, hi = lane >> 5;

  bf16x8 qf[4];
  {
    const u16* qp = Q + kbase + (size_t)(q0 + l31) * 64 + hi * 8;
#pragma unroll
    for (int d = 0; d < 4; ++d)
      qf[d] = *reinterpret_cast<const bf16x8*>(qp + d * 16);
  }

  f32x16 Oacc[2];
#pragma unroll
  for (int i = 0; i < 2; ++i)
#pragma unroll
    for (int r = 0; r < 16; ++r) Oacc[i][r] = 0.f;
  float m = -__builtin_inff(), lsum = 0.f;

  const char* gk0 = (const char*)(Kg + kbase);
  const char* gv0 = (const char*)(VTg + kbase);

#define STAGE(KT, BUF)                                                         \
  {                                                                            \
    char* lk_ = lds[BUF];                                                      \
    const char* gk_ = gk0 + (size_t)(sp * 16 + (KT)) * 8192;                   \
    _Pragma("unroll") for (int c_ = 0; c_ < 2; ++c_) {                         \
      int o_ = (c_ * 256 + t) * 16;                                            \
      int row_ = o_ >> 7, colb_ = o_ & 127;                                    \
      int swz_ = colb_ ^ ((row_ & 7) << 4);                                    \
      load_lds16(gk_ + row_ * 128 + swz_, lk_ + o_);                           \
      load_lds16(gv0 + (size_t)row_ * 4096 + sp * 2048 + (KT) * 128 + swz_,    \
                 lk_ + 8192 + o_);                                             \
    }                                                                          \
  }

  STAGE(0, 0)

  f32x16 Sa[2];
  for (int kt = 0; kt < NT; ++kt) {
    asm volatile("s_waitcnt vmcnt(0)" ::: "memory");
    __builtin_amdgcn_s_barrier();
    if (kt + 1 < NT) STAGE(kt + 1, (kt + 1) & 1)
    const char* lb = lds[kt & 1];
    qk_tile(lb, qf, Sa, l31, hi);
    sm_pv(lb + 8192, Sa, Oacc, m, lsum, l31, hi);
  }
#undef STAGE

  const float lfull = lsum + __shfl_xor(lsum, 32);
  const int srow = q0 + l31;
  const size_t rowi = (size_t)(sp * 32 + bh) * 2048 + srow;
  u16* prow = part + rowi * 64;
#pragma unroll
  for (int dt = 0; dt < 2; ++dt)
#pragma unroll
    for (int c = 0; c < 4; ++c) {
      uint2 pk;
      pk.x = (u32)f2bf(Oacc[dt][4 * c + 0]) | ((u32)f2bf(Oacc[dt][4 * c + 1]) << 16);
      pk.y = (u32)f2bf(Oacc[dt][4 * c + 2]) | ((u32)f2bf(Oacc[dt][4 * c + 3]) << 16);
      *reinterpret_cast<uint2*>(prow + dt * 32 + c * 8 + hi * 4) = pk;
    }
  if (hi == 0) stats[rowi] = make_float2(lfull, m);
}

// ---- merge the two KV-split partials (exact log-sum-exp combine) ----
__global__ __launch_bounds__(256) void attn_merge(const u16* __restrict__ part,
                                                  const float2* __restrict__ stats,
                                                  u16* __restrict__ attno) {
  int idx = blockIdx.x * 256 + threadIdx.x;  // 524288 = 65536 rows x 8 chunks
  int r = idx >> 3, c = idx & 7;
  float2 s0 = stats[r];
  float2 s1 = stats[65536 + r];
  float M = fmaxf(s0.y, s1.y);
  float w0 = exp2f(s0.y - M), w1 = exp2f(s1.y - M);
  float rden = 1.0f / (w0 * s0.x + w1 * s1.x);
  w0 *= rden; w1 *= rden;
  const uint4 a = *reinterpret_cast<const uint4*>(part + (size_t)r * 64 + c * 8);
  const uint4 b4 = *reinterpret_cast<const uint4*>(part + 4194304 + (size_t)r * 64 + c * 8);
  const u32 aw[4] = {a.x, a.y, a.z, a.w}, bw[4] = {b4.x, b4.y, b4.z, b4.w};
  u32 ow[4];
#pragma unroll
  for (int i = 0; i < 4; ++i) {
    float r0 = w0 * bf2f((u16)(aw[i] & 0xffffu)) + w1 * bf2f((u16)(bw[i] & 0xffffu));
    float r1 = w0 * bf2f((u16)(aw[i] >> 16)) + w1 * bf2f((u16)(bw[i] >> 16));
    ow[i] = (u32)f2bf(r0) | ((u32)f2bf(r1) << 16);
  }
  int bh = r >> 11, s = r & 2047;
  int b = bh >> 4, h = bh & 15;
  uint4 o; o.x = ow[0]; o.y = ow[1]; o.z = ow[2]; o.w = ow[3];
  *reinterpret_cast<uint4*>(attno + (size_t)(b * 2048 + s) * 1024 + h * 64 + c * 8) = o;
}

extern "C" void kernel_launch(void* const* d_in, const int* in_sizes, int n_in,
                              void* d_out, int out_size, void* d_ws, size_t ws_size,
                              hipStream_t stream) {
  (void)in_sizes; (void)n_in; (void)out_size; (void)ws_size;
  const float* x = (const float*)d_in[0];
  const float* wqkv = (const float*)d_in[1];
  const float* wout = (const float*)d_in[2];
  const int* pos = (const int*)d_in[3];
  float* out = (float*)d_out;

  char* ws = (char*)d_ws;
  u16* xb     = (u16*)(ws);             // 8 MB  x bf16 (dead after gemm_qkv)
  u16* wqkvb  = (u16*)(ws + 8388608);   // 6 MB  Wqkv bf16
  u16* woutb  = (u16*)(ws + 14680064);  // 2 MB  Wout bf16
  u16* vpack  = (u16*)(ws + 16777216);  // 8 MB  v bf16 [B*S][1024]
  u16* part   = (u16*)(ws + 25165824);  // 16 MB [2][32][2048][64] partials
  u16* qro    = (u16*)(ws + 41943040);  // 8 MB  q roped*0.125*log2e
  u16* kro    = (u16*)(ws + 50331648);  // 8 MB  k roped [BH][S][64]
  u16* vt     = (u16*)(ws + 58720256);  // 8 MB  v^T [BH][64][S]
  u16* attno  = (u16*)(ws + 67108864);  // 8 MB  attn out bf16 [4096][1024]
  float2* tab = (float2*)(ws + 75497472); // 512 KB trig table
  float2* stats = (float2*)(ws);        // 1 MB, overlays dead xb region

  prep_fused<<<8448, 256, 0, stream>>>(x, wqkv, wout, pos, xb, wqkvb, woutb, tab);
  gemm_qkv<<<dim3(24, 32), 256, 0, stream>>>(xb, wqkvb, tab, qro, kro, vpack);
  v_transpose<<<dim3(32, 32), 256, 0, stream>>>(vpack, vt);
  attn_split<<<1024, 256, 0, stream>>>(qro, kro, vt, part, stats);
  attn_merge<<<2048, 256, 0, stream>>>(part, stats, attno);
  gemm_out<<<dim3(8, 32), 256, 0, stream>>>(attno, woutb, out, 4096, 1024, 1024);
}

// Round 11
// 208.950 us; speedup vs baseline: 1.8583x; 1.0289x over previous
//
#include <hip/hip_runtime.h>
#include <stdint.h>

typedef unsigned short u16;
typedef unsigned int u32;
typedef __bf16 bf16x8 __attribute__((ext_vector_type(8)));
typedef float f32x4 __attribute__((ext_vector_type(4)));
typedef float f32x16 __attribute__((ext_vector_type(16)));

#define MFMA16 __builtin_amdgcn_mfma_f32_16x16x32_bf16
#define MFMA32 __builtin_amdgcn_mfma_f32_32x32x16_bf16

static __device__ __forceinline__ u16 f2bf(float f) {
  union { float f; u32 u; } v; v.f = f;
  u32 r = v.u + 0x7FFFu + ((v.u >> 16) & 1u);
  return (u16)(r >> 16);
}
static __device__ __forceinline__ float bf2f(u16 b) {
  union { float f; u32 u; } v; v.u = ((u32)b) << 16;
  return v.f;
}
static __device__ __forceinline__ void load_lds16(const void* g, void* l) {
  __builtin_amdgcn_global_load_lds(
      (const __attribute__((address_space(1))) void*)g,
      (__attribute__((address_space(3))) void*)l, 16, 0, 0);
}

// ------- prep: 3x fp32->bf16 convert + trig table, range-dispatched -------
__global__ __launch_bounds__(256) void prep_fused(const float* __restrict__ x,
                                                  const float* __restrict__ wqkv,
                                                  const float* __restrict__ wout,
                                                  const int* __restrict__ pos,
                                                  u16* __restrict__ xb,
                                                  u16* __restrict__ wqkvb,
                                                  u16* __restrict__ woutb,
                                                  float2* __restrict__ tab) {
  const int blk = blockIdx.x;
  if (blk < 8192) {  // converts: 2097152 float4-quads total
    int i = blk * 256 + threadIdx.x;
    const float* src;
    u16* dst;
    int off;
    if (i < 1048576) { src = x; dst = xb; off = i; }
    else if (i < 1835008) { src = wqkv; dst = wqkvb; off = i - 1048576; }
    else { src = wout; dst = woutb; off = i - 1835008; }
    float4 v = reinterpret_cast<const float4*>(src)[off];
    uint2 r;
    r.x = (u32)f2bf(v.x) | ((u32)f2bf(v.y) << 16);
    r.y = (u32)f2bf(v.z) | ((u32)f2bf(v.w) << 16);
    reinterpret_cast<uint2*>(dst)[off] = r;
  } else {  // trig: 65536 entries
    int i = (blk - 8192) * 256 + threadIdx.x;
    int s = i >> 5, p = i & 31;
    float inv = powf(10000.0f, -(float)p * (1.0f / 32.0f));
    float fr = (float)pos[s] * inv;
    float sn, cs;
    sincosf(fr, &sn, &cs);
    tab[i] = make_float2(cs, sn);
  }
}

// ---- QKV GEMM with fused RoPE epilogue ----
__global__ __launch_bounds__(256, 2) void gemm_qkv(const u16* __restrict__ A,
                                                   const u16* __restrict__ B,
                                                   const float2* __restrict__ tab,
                                                   u16* __restrict__ qro,
                                                   u16* __restrict__ kro,
                                                   u16* __restrict__ vpack) {
  constexpr int K = 1024;
  __shared__ u16 As[128 * 32];
  __shared__ u16 Bs[128 * 32];
  const int t = threadIdx.x;
  const int w = t >> 6, lane = t & 63;
  const int brow = blockIdx.y * 128, bcol = blockIdx.x * 128;
  const int wr = (w >> 1) * 64, wc = (w & 1) * 64;

  f32x4 acc[4][4];
#pragma unroll
  for (int i = 0; i < 4; ++i)
#pragma unroll
    for (int j = 0; j < 4; ++j) acc[i][j] = (f32x4){0.f, 0.f, 0.f, 0.f};

  const int srow = w * 16 + (lane >> 2);
  const int scol = (lane & 3) * 8;
  const u16* ga = A + (size_t)(brow + srow) * K + scol;
  const u16* gb = B + (size_t)(bcol + srow) * K + scol;
  const size_t rstep = (size_t)64 * K;
  u16* ldsA = As + w * 512;
  u16* ldsB = Bs + w * 512;

  const int lc = lane & 15, lg = lane >> 4;
  const int kg = lg * 8;

  for (int kt = 0; kt < K / 32; ++kt) {
    __syncthreads();
    load_lds16(ga, ldsA);
    load_lds16(ga + rstep, (char*)ldsA + 4096);
    load_lds16(gb, ldsB);
    load_lds16(gb + rstep, (char*)ldsB + 4096);
    ga += 32; gb += 32;
    asm volatile("s_waitcnt vmcnt(0)" ::: "memory");
    __syncthreads();
    bf16x8 af[4], bfr[4];
#pragma unroll
    for (int i = 0; i < 4; ++i)
      af[i] = *reinterpret_cast<const bf16x8*>(As + (wr + i * 16 + lc) * 32 + kg);
#pragma unroll
    for (int j = 0; j < 4; ++j)
      bfr[j] = *reinterpret_cast<const bf16x8*>(Bs + (wc + j * 16 + lc) * 32 + kg);
#pragma unroll
    for (int i = 0; i < 4; ++i)
#pragma unroll
      for (int j = 0; j < 4; ++j)
        acc[i][j] = MFMA16(af[i], bfr[j], acc[i][j], 0, 0, 0);
  }

  const int r0 = lg * 4;
  if (bcol >= 2048) {
#pragma unroll
    for (int i = 0; i < 4; ++i)
#pragma unroll
      for (int j = 0; j < 4; ++j)
#pragma unroll
        for (int r = 0; r < 4; ++r) {
          const int m = brow + wr + i * 16 + r0 + r;
          const int n = bcol + wc + j * 16 + lc;
          vpack[(size_t)m * 1024 + (n - 2048)] = f2bf(acc[i][j][r]);
        }
  } else {
    const bool isq = bcol < 1024;
    u16* dst = isq ? qro : kro;
    const float scale = isq ? 0.18033688011112042f : 1.0f;  // 0.125*log2e
#pragma unroll
    for (int i = 0; i < 4; ++i)
#pragma unroll
      for (int j = 0; j < 4; ++j)
#pragma unroll
        for (int r = 0; r < 4; ++r) {
          const int m = brow + wr + i * 16 + r0 + r;
          const int n = bcol + wc + j * 16 + lc;
          const int nn = n & 1023;
          const int h = nn >> 6, d = nn & 63, p = d >> 1;
          const int s = m & 2047, b = m >> 11;
          float val = acc[i][j][r];
          float pv = __shfl_xor(val, 1);  // partner element of the RoPE pair
          float2 cssn = tab[s * 32 + p];
          float o = (d & 1) ? (pv * cssn.y + val * cssn.x)
                            : (val * cssn.x - pv * cssn.y);
          dst[((size_t)(b * 16 + h) * 2048 + s) * 64 + d] = f2bf(o * scale);
        }
  }
}

// ---------------- output GEMM: C[M][N] = A[M][K] @ B[N][K]^T, fp32 out ----
__global__ __launch_bounds__(256, 2) void gemm_out(const u16* __restrict__ A,
                                                   const u16* __restrict__ B,
                                                   float* __restrict__ C,
                                                   int M, int N, int K) {
  __shared__ u16 As[128 * 32];
  __shared__ u16 Bs[128 * 32];
  const int t = threadIdx.x;
  const int w = t >> 6, lane = t & 63;
  const int brow = blockIdx.y * 128, bcol = blockIdx.x * 128;
  const int wr = (w >> 1) * 64, wc = (w & 1) * 64;

  f32x4 acc[4][4];
#pragma unroll
  for (int i = 0; i < 4; ++i)
#pragma unroll
    for (int j = 0; j < 4; ++j) acc[i][j] = (f32x4){0.f, 0.f, 0.f, 0.f};

  const int srow = w * 16 + (lane >> 2);
  const int scol = (lane & 3) * 8;
  const u16* ga = A + (size_t)(brow + srow) * K + scol;
  const u16* gb = B + (size_t)(bcol + srow) * K + scol;
  const size_t rstep = (size_t)64 * K;
  u16* ldsA = As + w * 512;
  u16* ldsB = Bs + w * 512;

  const int lc = lane & 15, lg = lane >> 4;
  const int kg = lg * 8;

  const int nk = K >> 5;
  for (int kt = 0; kt < nk; ++kt) {
    __syncthreads();
    load_lds16(ga, ldsA);
    load_lds16(ga + rstep, (char*)ldsA + 4096);
    load_lds16(gb, ldsB);
    load_lds16(gb + rstep, (char*)ldsB + 4096);
    ga += 32; gb += 32;
    asm volatile("s_waitcnt vmcnt(0)" ::: "memory");
    __syncthreads();
    bf16x8 af[4], bfr[4];
#pragma unroll
    for (int i = 0; i < 4; ++i)
      af[i] = *reinterpret_cast<const bf16x8*>(As + (wr + i * 16 + lc) * 32 + kg);
#pragma unroll
    for (int j = 0; j < 4; ++j)
      bfr[j] = *reinterpret_cast<const bf16x8*>(Bs + (wc + j * 16 + lc) * 32 + kg);
#pragma unroll
    for (int i = 0; i < 4; ++i)
#pragma unroll
      for (int j = 0; j < 4; ++j)
        acc[i][j] = MFMA16(af[i], bfr[j], acc[i][j], 0, 0, 0);
  }

  const int r0 = lg * 4;
#pragma unroll
  for (int i = 0; i < 4; ++i)
#pragma unroll
    for (int j = 0; j < 4; ++j)
#pragma unroll
      for (int r = 0; r < 4; ++r) {
        const int m = brow + wr + i * 16 + r0 + r;
        const int n = bcol + wc + j * 16 + lc;
        C[(size_t)m * N + n] = acc[i][j][r];
      }
}

// ---------------- V -> V^T   (vpack[B*S][1024] -> [B*H][64][S]) ----
__global__ __launch_bounds__(256) void v_transpose(const u16* __restrict__ vpack,
                                                   u16* __restrict__ VT) {
  const int bh = blockIdx.y;
  const int s0 = blockIdx.x * 64;
  const int b = bh >> 4, h = bh & 15;
  __shared__ u16 tile[64][72];
  const int t = threadIdx.x;
#pragma unroll
  for (int c = 0; c < 2; ++c) {
    int r = c * 32 + (t >> 3);
    int d = (t & 7) * 8;
    const u16* src = vpack + (size_t)(b * 2048 + s0 + r) * 1024 + h * 64 + d;
    *reinterpret_cast<uint4*>(&tile[r][d]) = *reinterpret_cast<const uint4*>(src);
  }
  __syncthreads();
#pragma unroll
  for (int c = 0; c < 2; ++c) {
    int dd = c * 32 + (t >> 3);
    int sg = (t & 7) * 8;
    u16 tmp[8];
#pragma unroll
    for (int jj = 0; jj < 8; ++jj) tmp[jj] = tile[sg + jj][dd];
    *reinterpret_cast<uint4*>(VT + ((size_t)bh * 64 + dd) * 2048 + s0 + sg) =
        *reinterpret_cast<const uint4*>(tmp);
  }
}

// ======== flash attention r10: no-max softmax (m=0), 64 q-rows/wave ========
// Logits are hard-bounded (|s| <= ~22 in exp2 domain) -> fixed m=0 is
// numerically safe in fp32; normalization cancels scale exactly. Each K/V
// fragment read from LDS feeds TWO row-group MFMAs -> LDS traffic per unit
// work halves. Grid 512 (32 bh x 4 qb(256 rows) x 2 KV-splits).

static __device__ __forceinline__ void pack_p(const f32x16 (&SA)[2],
                                              bf16x8 (&pf)[4]) {
#pragma unroll
  for (int kvt = 0; kvt < 2; ++kvt)
#pragma unroll
    for (int s1 = 0; s1 < 2; ++s1) {
      u32 X0, X1, Y0, Y1;
      const int c0 = s1 * 8, c1 = c0 + 4;
      asm("v_cvt_pk_bf16_f32 %0, %1, %2"
          : "=v"(X0) : "v"(SA[kvt][c0 + 0]), "v"(SA[kvt][c0 + 1]));
      asm("v_cvt_pk_bf16_f32 %0, %1, %2"
          : "=v"(X1) : "v"(SA[kvt][c0 + 2]), "v"(SA[kvt][c0 + 3]));
      asm("v_cvt_pk_bf16_f32 %0, %1, %2"
          : "=v"(Y0) : "v"(SA[kvt][c1 + 0]), "v"(SA[kvt][c1 + 1]));
      asm("v_cvt_pk_bf16_f32 %0, %1, %2"
          : "=v"(Y1) : "v"(SA[kvt][c1 + 2]), "v"(SA[kvt][c1 + 3]));
      asm("v_permlane32_swap_b32 %0, %1" : "+v"(X0), "+v"(Y0));
      asm("v_permlane32_swap_b32 %0, %1" : "+v"(X1), "+v"(Y1));
      union { u32 w[4]; bf16x8 v; } u;
      u.w[0] = X0; u.w[1] = X1; u.w[2] = Y0; u.w[3] = Y1;
      pf[kvt * 2 + s1] = u.v;
    }
}

__global__ __launch_bounds__(256, 2) void attn_split(const u16* __restrict__ Q,
                                                     const u16* __restrict__ Kg,
                                                     const u16* __restrict__ VTg,
                                                     u16* __restrict__ part,
                                                     float2* __restrict__ stats) {
  constexpr int S = 2048, NT = 16;
  __shared__ char lds[2][16384];
  const int t = threadIdx.x, wv = t >> 6, lane = t & 63;
  const int bid = blockIdx.x;  // 512 blocks
  const int slot = bid >> 3;   // 0..63
  const int bh = (bid & 7) * 4 + (slot >> 4);
  const int rest = slot & 15;
  const int qb = rest >> 1, sp = rest & 1;
  const int q0 = qb * 256 + wv * 64;
  const size_t kbase = (size_t)bh * (S * 64);
  const int l31 = lane & 31, hi = lane >> 5;

  bf16x8 qf0[4], qf1[4];
  {
    const u16* qp = Q + kbase + (size_t)(q0 + l31) * 64 + hi * 8;
#pragma unroll
    for (int d = 0; d < 4; ++d) {
      qf0[d] = *reinterpret_cast<const bf16x8*>(qp + d * 16);
      qf1[d] = *reinterpret_cast<const bf16x8*>(qp + 32 * 64 + d * 16);
    }
  }

  f32x16 Oacc[2][2];
#pragma unroll
  for (int g = 0; g < 2; ++g)
#pragma unroll
    for (int i = 0; i < 2; ++i)
#pragma unroll
      for (int r = 0; r < 16; ++r) Oacc[g][i][r] = 0.f;
  float lsum0 = 0.f, lsum1 = 0.f;

  const char* gk0 = (const char*)(Kg + kbase);
  const char* gv0 = (const char*)(VTg + kbase);

#define STAGE(KT, BUF)                                                         \
  {                                                                            \
    char* lk_ = lds[BUF];                                                      \
    const char* gk_ = gk0 + (size_t)(sp * 16 + (KT)) * 8192;                   \
    _Pragma("unroll") for (int c_ = 0; c_ < 2; ++c_) {                         \
      int o_ = (c_ * 256 + t) * 16;                                            \
      int row_ = o_ >> 7, colb_ = o_ & 127;                                    \
      int swz_ = colb_ ^ ((row_ & 7) << 4);                                    \
      load_lds16(gk_ + row_ * 128 + swz_, lk_ + o_);                           \
      load_lds16(gv0 + (size_t)row_ * 4096 + sp * 2048 + (KT) * 128 + swz_,    \
                 lk_ + 8192 + o_);                                             \
    }                                                                          \
  }

  STAGE(0, 0)

  for (int kt = 0; kt < NT; ++kt) {
    asm volatile("s_waitcnt vmcnt(0)" ::: "memory");
    __builtin_amdgcn_s_barrier();
    if (kt + 1 < NT) STAGE(kt + 1, (kt + 1) & 1)
    const char* lk = lds[kt & 1];
    const char* lv = lk + 8192;

    // ---- QK^T for both row-groups; each kf feeds 2 MFMAs ----
    f32x16 Sa0[2], Sa1[2];
#pragma unroll
    for (int i = 0; i < 2; ++i)
#pragma unroll
      for (int r = 0; r < 16; ++r) { Sa0[i][r] = 0.f; Sa1[i][r] = 0.f; }
    __builtin_amdgcn_s_setprio(1);
#pragma unroll
    for (int d = 0; d < 4; ++d)
#pragma unroll
      for (int kvt = 0; kvt < 2; ++kvt) {
        int kv = kvt * 32 + l31;
        int a = (kv * 128 + d * 32 + hi * 16) ^ ((kv & 7) << 4);
        bf16x8 kf = *reinterpret_cast<const bf16x8*>(lk + a);
        Sa0[kvt] = MFMA32(kf, qf0[d], Sa0[kvt], 0, 0, 0);
        Sa1[kvt] = MFMA32(kf, qf1[d], Sa1[kvt], 0, 0, 0);
      }
    __builtin_amdgcn_s_setprio(0);

    // ---- P = exp2(S) directly (fixed m=0), per-lane partial sums ----
#pragma unroll
    for (int kvt = 0; kvt < 2; ++kvt)
#pragma unroll
      for (int r = 0; r < 16; ++r) {
        Sa0[kvt][r] = exp2f(Sa0[kvt][r]);
        Sa1[kvt][r] = exp2f(Sa1[kvt][r]);
      }
    {
      float st0[16], st1[16];
#pragma unroll
      for (int r = 0; r < 16; ++r) {
        st0[r] = Sa0[0][r] + Sa0[1][r];
        st1[r] = Sa1[0][r] + Sa1[1][r];
      }
#pragma unroll
      for (int d = 8; d >= 1; d >>= 1)
#pragma unroll
        for (int r = 0; r < d; ++r) { st0[r] += st0[r + d]; st1[r] += st1[r + d]; }
      lsum0 += st0[0];
      lsum1 += st1[0];
    }

    // ---- pack both groups, then joint PV (each vf feeds 2 MFMAs) ----
    bf16x8 pf0[4], pf1[4];
    pack_p(Sa0, pf0);
    pack_p(Sa1, pf1);

    __builtin_amdgcn_s_setprio(1);
#pragma unroll
    for (int s = 0; s < 4; ++s)
#pragma unroll
      for (int dt = 0; dt < 2; ++dt) {
        int d = dt * 32 + l31;
        int a = (d * 128 + s * 32 + hi * 16) ^ ((d & 7) << 4);
        bf16x8 vf = *reinterpret_cast<const bf16x8*>(lv + a);
        Oacc[0][dt] = MFMA32(vf, pf0[s], Oacc[0][dt], 0, 0, 0);
        Oacc[1][dt] = MFMA32(vf, pf1[s], Oacc[1][dt], 0, 0, 0);
      }
    __builtin_amdgcn_s_setprio(0);
  }
#undef STAGE

  // ---- epilogue: unnormalized bf16 partials + (l, m=0) stats ----
#pragma unroll
  for (int g = 0; g < 2; ++g) {
    float lsum = g ? lsum1 : lsum0;
    const float lfull = lsum + __shfl_xor(lsum, 32);
    const int srow = q0 + g * 32 + l31;
    const size_t rowi = (size_t)(sp * 32 + bh) * 2048 + srow;
    u16* prow = part + rowi * 64;
#pragma unroll
    for (int dt = 0; dt < 2; ++dt)
#pragma unroll
      for (int c = 0; c < 4; ++c) {
        float a0 = Oacc[g][dt][4 * c + 0], a1 = Oacc[g][dt][4 * c + 1];
        float a2 = Oacc[g][dt][4 * c + 2], a3 = Oacc[g][dt][4 * c + 3];
        uint2 pk;
        pk.x = (u32)f2bf(a0) | ((u32)f2bf(a1) << 16);
        pk.y = (u32)f2bf(a2) | ((u32)f2bf(a3) << 16);
        *reinterpret_cast<uint2*>(prow + dt * 32 + c * 8 + hi * 4) = pk;
      }
    if (hi == 0) stats[rowi] = make_float2(lfull, 0.0f);
  }
}

// ---- merge the two KV-split partials (exact log-sum-exp combine) ----
__global__ __launch_bounds__(256) void attn_merge(const u16* __restrict__ part,
                                                  const float2* __restrict__ stats,
                                                  u16* __restrict__ attno) {
  int idx = blockIdx.x * 256 + threadIdx.x;  // 524288 = 65536 rows x 8 chunks
  int r = idx >> 3, c = idx & 7;
  float2 s0 = stats[r];
  float2 s1 = stats[65536 + r];
  float M = fmaxf(s0.y, s1.y);
  float w0 = exp2f(s0.y - M), w1 = exp2f(s1.y - M);
  float rden = 1.0f / (w0 * s0.x + w1 * s1.x);
  w0 *= rden; w1 *= rden;
  const uint4 a = *reinterpret_cast<const uint4*>(part + (size_t)r * 64 + c * 8);
  const uint4 b4 = *reinterpret_cast<const uint4*>(part + 4194304 + (size_t)r * 64 + c * 8);
  const u32 aw[4] = {a.x, a.y, a.z, a.w}, bw[4] = {b4.x, b4.y, b4.z, b4.w};
  u32 ow[4];
#pragma unroll
  for (int i = 0; i < 4; ++i) {
    float r0 = w0 * bf2f((u16)(aw[i] & 0xffffu)) + w1 * bf2f((u16)(bw[i] & 0xffffu));
    float r1 = w0 * bf2f((u16)(aw[i] >> 16)) + w1 * bf2f((u16)(bw[i] >> 16));
    ow[i] = (u32)f2bf(r0) | ((u32)f2bf(r1) << 16);
  }
  int bh = r >> 11, s = r & 2047;
  int b = bh >> 4, h = bh & 15;
  uint4 o; o.x = ow[0]; o.y = ow[1]; o.z = ow[2]; o.w = ow[3];
  *reinterpret_cast<uint4*>(attno + (size_t)(b * 2048 + s) * 1024 + h * 64 + c * 8) = o;
}

extern "C" void kernel_launch(void* const* d_in, const int* in_sizes, int n_in,
                              void* d_out, int out_size, void* d_ws, size_t ws_size,
                              hipStream_t stream) {
  (void)in_sizes; (void)n_in; (void)out_size; (void)ws_size;
  const float* x = (const float*)d_in[0];
  const float* wqkv = (const float*)d_in[1];
  const float* wout = (const float*)d_in[2];
  const int* pos = (const int*)d_in[3];
  float* out = (float*)d_out;

  char* ws = (char*)d_ws;
  u16* xb     = (u16*)(ws);             // 8 MB  x bf16 (dead after gemm_qkv)
  u16* wqkvb  = (u16*)(ws + 8388608);   // 6 MB  Wqkv bf16
  u16* woutb  = (u16*)(ws + 14680064);  // 2 MB  Wout bf16
  u16* vpack  = (u16*)(ws + 16777216);  // 8 MB  v bf16 [B*S][1024]
  u16* part   = (u16*)(ws + 25165824);  // 16 MB [2][32][2048][64] partials
  u16* qro    = (u16*)(ws + 41943040);  // 8 MB  q roped*0.125*log2e
  u16* kro    = (u16*)(ws + 50331648);  // 8 MB  k roped [BH][S][64]
  u16* vt     = (u16*)(ws + 58720256);  // 8 MB  v^T [BH][64][S]
  u16* attno  = (u16*)(ws + 67108864);  // 8 MB  attn out bf16 [4096][1024]
  float2* tab = (float2*)(ws + 75497472); // 512 KB trig table
  float2* stats = (float2*)(ws);        // 1 MB, overlays dead xb region

  prep_fused<<<8448, 256, 0, stream>>>(x, wqkv, wout, pos, xb, wqkvb, woutb, tab);
  gemm_qkv<<<dim3(24, 32), 256, 0, stream>>>(xb, wqkvb, tab, qro, kro, vpack);
  v_transpose<<<dim3(32, 32), 256, 0, stream>>>(vpack, vt);
  attn_split<<<512, 256, 0, stream>>>(qro, kro, vt, part, stats);
  attn_merge<<<2048, 256, 0, stream>>>(part, stats, attno);
  gemm_out<<<dim3(8, 32), 256, 0, stream>>>(attno, woutb, out, 4096, 1024, 1024);
}